// Round 8
// baseline (366.621 us; speedup 1.0000x reference)
//
#include <hip/hip_runtime.h>
#include <math.h>

#define BB 16
#define CC 32
#define OO 32
#define HH 256
#define WW 256
#define HW (HH * WW)
#define PD 8
#define HP (HH + 2 * PD)      // 272
#define WP (WW + 2 * PD)      // 272

typedef __attribute__((ext_vector_type(8))) short bf16x8;
typedef __attribute__((ext_vector_type(4))) float f32x4;
typedef __attribute__((ext_vector_type(4))) unsigned short us4;
typedef __attribute__((ext_vector_type(8))) unsigned short us8;

__device__ __forceinline__ unsigned short f2bf(float f) {
    unsigned u = __float_as_uint(f);
    u += 0x7fffu + ((u >> 16) & 1u);     // round-to-nearest-even
    return (unsigned short)(u >> 16);
}
__device__ __forceinline__ float bf2f(unsigned short v) {
    return __uint_as_float((unsigned)v << 16);
}

// ---------------------------------------------------------------------------
// Kernel 1: 5x5 separable Gaussian blur -> zero-padded channels-last bf16
//   xbt[b][y=h+PD][x=w+PD][c].  (unchanged from R5)
// ---------------------------------------------------------------------------
__global__ __launch_bounds__(256) void blur_t_kernel(const float* __restrict__ x,
                                                     const float* __restrict__ sigma_p,
                                                     unsigned short* __restrict__ xbt) {
    __shared__ __align__(16) unsigned short vb[16][4][264];   // [c%16][row][col+4]
    const int t   = threadIdx.x;
    const int blk = ((blockIdx.x & 7) << 7) + (blockIdx.x >> 3);   // 1024 blocks, chunk 128
    const int band = blk & 63;
    const int b    = blk >> 6;
    const int h0   = band << 2;

    const float sigma = sigma_p[0];
    const float inv2s2 = 1.0f / (2.0f * sigma * sigma);
    float e[5], s = 0.0f;
#pragma unroll
    for (int i = 0; i < 5; ++i) {
        float d = (float)(i - 2);
        e[i] = expf(-(d * d) * inv2s2);
        s += e[i];
    }
    const float inv_s = 1.0f / s;
    float wn[5];
#pragma unroll
    for (int i = 0; i < 5; ++i) wn[i] = e[i] * inv_s;

    unsigned short* xb_img = xbt + (size_t)b * (HP * WP * CC);

    // ---- halo zeroing ----
    const us8 z8 = {0, 0, 0, 0, 0, 0, 0, 0};
    {
        const int j  = t >> 6;
        const int px = (t >> 2) & 15;
        const int ch = t & 3;
        const int xx = (px < PD) ? px : px + WW;
        *reinterpret_cast<us8*>(xb_img + ((size_t)(h0 + PD + j) * WP + xx) * CC + ch * 8) = z8;
    }
    if (h0 < PD) {
#pragma unroll
        for (int j2 = 0; j2 < 4; ++j2) {
            unsigned short* dst = xb_img + (size_t)(h0 + j2) * WP * CC;
            for (int i = t; i < (WP * CC) / 8; i += 256)
                *reinterpret_cast<us8*>(dst + i * 8) = z8;
        }
    }
    if (h0 + 4 > HH - PD) {
#pragma unroll
        for (int j2 = 0; j2 < 4; ++j2) {
            unsigned short* dst = xb_img + (size_t)(h0 + j2 + 2 * PD) * WP * CC;
            for (int i = t; i < (WP * CC) / 8; i += 256)
                *reinterpret_cast<us8*>(dst + i * 8) = z8;
        }
    }

    const int g  = t & 63;
    const int cs = t >> 6;

#pragma unroll
    for (int pass = 0; pass < 2; ++pass) {
        if (pass) __syncthreads();

        {
            const int c15 = t >> 4;
            const int j   = (t >> 2) & 3;
            const int e_  = t & 3;
            const int idx = (e_ < 2) ? (2 + e_) : (258 + e_);
            vb[c15][j][idx] = 0;
        }

#pragma unroll
        for (int it = 0; it < 4; ++it) {
            const int c = (pass << 4) + (it << 2) + cs;
            const float* xc = x + ((size_t)(b * CC + c) * HH) * WW + 4 * g;
            float4 v[8];
#pragma unroll
            for (int k = 0; k < 8; ++k) {
                const int r = h0 - 2 + k;
                v[k] = (r >= 0 && r < HH) ? *reinterpret_cast<const float4*>(xc + r * WW)
                                          : make_float4(0.f, 0.f, 0.f, 0.f);
            }
#pragma unroll
            for (int j = 0; j < 4; ++j) {
                float4 a = make_float4(0.f, 0.f, 0.f, 0.f);
#pragma unroll
                for (int i = 0; i < 5; ++i) {
                    a.x = fmaf(wn[i], v[j + i].x, a.x);
                    a.y = fmaf(wn[i], v[j + i].y, a.y);
                    a.z = fmaf(wn[i], v[j + i].z, a.z);
                    a.w = fmaf(wn[i], v[j + i].w, a.w);
                }
                us4 bv;
                bv[0] = f2bf(a.x); bv[1] = f2bf(a.y);
                bv[2] = f2bf(a.z); bv[3] = f2bf(a.w);
                *reinterpret_cast<us4*>(&vb[c & 15][j][4 + 4 * g]) = bv;
            }
        }
        __syncthreads();

        const int c15 = t & 15;
        const int c   = (pass << 4) + c15;
        const int T   = t >> 4;
#pragma unroll
        for (int j = 0; j < 4; ++j) {
            us4 ch[6];
#pragma unroll
            for (int k = 0; k < 6; ++k)
                ch[k] = *reinterpret_cast<const us4*>(&vb[c15][j][16 * T + 4 * k]);
            float val[24];
#pragma unroll
            for (int q = 0; q < 24; ++q) val[q] = bf2f(ch[q >> 2][q & 3]);
            unsigned short* ob = xb_img + ((size_t)(h0 + PD + j) * WP + PD + 16 * T) * CC + c;
#pragma unroll
            for (int d = 0; d < 16; ++d) {
                float a = 0.0f;
#pragma unroll
                for (int i = 0; i < 5; ++i) a = fmaf(wn[i], val[d + 2 + i], a);
                ob[d * CC] = f2bf(a);
            }
        }
    }
}

// ---------------------------------------------------------------------------
// Kernel 2: corner table (SORTED by image offset => row-major locality) +
// pre-scaled B fragments. (unchanged from R6)
// ---------------------------------------------------------------------------
__global__ void wtrans_kernel(const float* __restrict__ wgt,
                              const float* __restrict__ sigma_p,
                              int* __restrict__ meta,
                              unsigned short* __restrict__ wb2) {
    __shared__ int   s_tap[36];
    __shared__ float s_w[36];
    __shared__ int   s_soff[36];
    __shared__ int   s_n;
    const int t = threadIdx.x;

    if (t == 0) {
        const float UY[9] = {-0.70710678f, -1.0f, -0.70710678f, 0.0f, 0.0f, 0.0f,
                              0.70710678f,  1.0f,  0.70710678f};
        const float UX[9] = {-0.70710678f, 0.0f, 0.70710678f, -1.0f, 0.0f, 1.0f,
                             -0.70710678f, 0.0f, 0.70710678f};
        const int KYI[9] = {-1, -1, -1, 0, 0, 0, 1, 1, 1};
        const int KXI[9] = {-1, 0, 1, -1, 0, 1, -1, 0, 1};
        const float s6 = sigma_p[0] * 6.0f;
        int n = 0;
        for (int s_ = 0; s_ < 9; ++s_) {
            float offy = UY[s_] * s6, offx = UX[s_] * s6;
            float fy = floorf(offy), fx = floorf(offx);
            float ty = offy - fy,    tx = offx - fx;
            int sy = KYI[s_] + (int)fy;
            int sx = KXI[s_] + (int)fx;
            float wy[2] = {1.0f - ty, ty};
            float wx[2] = {1.0f - tx, tx};
            for (int dy = 0; dy < 2; ++dy)
                for (int dx = 0; dx < 2; ++dx) {
                    float wc = wy[dy] * wx[dx];
                    if (wc != 0.0f) {
                        s_tap[n]  = s_;
                        s_w[n]    = wc;
                        s_soff[n] = ((sy + dy) * WP + (sx + dx)) * CC;
                        ++n;
                    }
                }
        }
        // insertion sort by soff (== row-major (Sy,Sx) order)
        for (int i = 1; i < n; ++i) {
            int ks = s_soff[i]; int kt = s_tap[i]; float kw = s_w[i];
            int j = i - 1;
            while (j >= 0 && s_soff[j] > ks) {
                s_soff[j + 1] = s_soff[j]; s_tap[j + 1] = s_tap[j]; s_w[j + 1] = s_w[j];
                --j;
            }
            s_soff[j + 1] = ks; s_tap[j + 1] = kt; s_w[j + 1] = kw;
        }
        if (blockIdx.x == 0) {
            meta[0] = n;
            for (int i = 0; i < n; ++i) meta[1 + i] = s_soff[i];
        }
        s_n = n;
    }
    __syncthreads();

    const int e = blockIdx.x;
    if (e >= s_n) return;
    for (int i = t; i < 1024; i += 256) {
        int j  = i & 7;
        int l  = (i >> 3) & 63;
        int nh = (i >> 9) & 1;
        int o  = nh * 16 + (l & 15);
        int c  = ((l >> 4) << 3) + j;
        wb2[e * 1024 + i] = f2bf(s_w[e] * wgt[(o * CC + c) * 9 + s_tap[e]]);
    }
}

// ---------------------------------------------------------------------------
// Kernel 3: pure-MFMA mix with a COMPILE-TIME-UNROLLED 21-entry path.
// sigma=1.0 -> exactly 21 corner entries; full unroll lets the compiler hoist
// all meta s_loads and pipeline A-loads entries ahead of their MFMAs (the R7
// profile showed a serial per-iteration latency chain: MfmaUtil 15% with
// nothing saturated). Generic loop fallback keeps correctness for any sigma.
// Block = 8 waves = 4 rows x 2 x-segments; B staged in 43 KB LDS -> 3 blk/CU.
// ---------------------------------------------------------------------------
#define NE 21

#define MIX_BODY(E, B0EXPR, B1EXPR)                                            \
    {                                                                          \
        const int soff_ = meta[1 + (E)];                                       \
        const bf16x8 b0_ = (B0EXPR);                                           \
        const bf16x8 b1_ = (B1EXPR);                                           \
        const unsigned short* pe_ = rowp + soff_ + loff;                       \
        _Pragma("unroll")                                                      \
        for (int tt = 0; tt < 8; ++tt) {                                       \
            const bf16x8 a_ = *reinterpret_cast<const bf16x8*>(pe_ + tt * 512);\
            acc[tt][0] = __builtin_amdgcn_mfma_f32_16x16x32_bf16(a_, b0_, acc[tt][0], 0, 0, 0); \
            acc[tt][1] = __builtin_amdgcn_mfma_f32_16x16x32_bf16(a_, b1_, acc[tt][1], 0, 0, 0); \
        }                                                                      \
    }

__global__ __launch_bounds__(512, 6) void mix5_kernel(const unsigned short* __restrict__ xbt,
                                                      const int* __restrict__ meta,
                                                      const unsigned short* __restrict__ wb2,
                                                      float* __restrict__ out) {
    __shared__ us8 bs8[NE * 128];            // 21 entries x 2 KB = 43 KB
    const int t    = threadIdx.x;
    const int lane = t & 63;
    const int wv   = t >> 6;                 // 0..7
    const int blk  = ((blockIdx.x & 7) << 7) + (blockIdx.x >> 3);  // 1024 blocks, chunk 128
    const int b    = blk >> 6;
    const int h    = ((blk & 63) << 2) + (wv >> 1);
    const int xseg = (wv & 1) << 7;          // 0 or 128
    const int mrow = lane & 15;
    const int c0   = (lane >> 4) << 3;
    const int ncorn = meta[0];
    const int nl    = min(ncorn, NE);

    // stage B entries 0..nl-1 into LDS
    for (int i = t; i < nl * 128; i += 512)
        bs8[i] = reinterpret_cast<const us8*>(wb2)[i];
    __syncthreads();

    const unsigned short* rowp = xbt + ((size_t)(b * HP + h + PD) * WP + PD) * CC;
    const int loff = (xseg + mrow) * CC + c0;

    f32x4 acc[8][2];
#pragma unroll
    for (int tt = 0; tt < 8; ++tt) {
        acc[tt][0] = (f32x4){0.f, 0.f, 0.f, 0.f};
        acc[tt][1] = (f32x4){0.f, 0.f, 0.f, 0.f};
    }

    const unsigned short* bsp = reinterpret_cast<const unsigned short*>(bs8);

    if (ncorn == NE) {
        // specialized fully-unrolled path (sigma=1.0 and most sigmas)
#pragma unroll
        for (int e = 0; e < NE; ++e)
            MIX_BODY(e,
                     *reinterpret_cast<const bf16x8*>(bsp + (e * 128 + lane) * 8),
                     *reinterpret_cast<const bf16x8*>(bsp + (e * 128 + 64 + lane) * 8));
    } else {
        for (int e = 0; e < ncorn; ++e) {
            if (e < NE) {
                MIX_BODY(e,
                         *reinterpret_cast<const bf16x8*>(bsp + (e * 128 + lane) * 8),
                         *reinterpret_cast<const bf16x8*>(bsp + (e * 128 + 64 + lane) * 8));
            } else {
                MIX_BODY(e,
                         *reinterpret_cast<const bf16x8*>(wb2 + ((e * 2 + 0) * 64 + lane) * 8),
                         *reinterpret_cast<const bf16x8*>(wb2 + ((e * 2 + 1) * 64 + lane) * 8));
            }
        }
    }

    // D: out channel = lane&15 (+16 for acc1), pixel = xseg + tt*16 + (lane>>4)*4 + j
    const int prow = (lane >> 4) << 2;
    float* op0 = out + ((size_t)b * OO + (lane & 15)) * HW + (size_t)h * WW + xseg + prow;
#pragma unroll
    for (int tt = 0; tt < 8; ++tt) {
        *reinterpret_cast<f32x4*>(op0 + tt * 16) = acc[tt][0];
        *reinterpret_cast<f32x4*>(op0 + tt * 16 + (size_t)16 * HW) = acc[tt][1];
    }
}

// ---------------------------------------------------------------------------
extern "C" void kernel_launch(void* const* d_in, const int* in_sizes, int n_in,
                              void* d_out, int out_size, void* d_ws, size_t ws_size,
                              hipStream_t stream) {
    const float* x     = (const float*)d_in[0];
    const float* sigma = (const float*)d_in[1];
    const float* wgt   = (const float*)d_in[2];
    float* out = (float*)d_out;

    // ws layout: [ meta: 64 ints ][ wb2: 36*1024 bf16 ] (128 KB reserved)
    //            [ xbt: BB*HP*WP*CC bf16 padded image ]
    int* meta           = (int*)d_ws;
    unsigned short* wb2 = (unsigned short*)((char*)d_ws + 256);
    unsigned short* xbt = (unsigned short*)((char*)d_ws + 131072);

    wtrans_kernel<<<36, 256, 0, stream>>>(wgt, sigma, meta, wb2);
    blur_t_kernel<<<BB * 64, 256, 0, stream>>>(x, sigma, xbt);
    mix5_kernel<<<BB * 64, 512, 0, stream>>>(xbt, meta, wb2, out);
}

// Round 9
// 321.701 us; speedup vs baseline: 1.1396x; 1.1396x over previous
//
#include <hip/hip_runtime.h>
#include <math.h>

#define BB 16
#define CC 32
#define OO 32
#define HH 256
#define WW 256
#define HW (HH * WW)
#define PD 8
#define HP (HH + 2 * PD)      // 272
#define WP (WW + 2 * PD)      // 272
#define NEMAX 36

typedef __attribute__((ext_vector_type(8))) short bf16x8;
typedef __attribute__((ext_vector_type(4))) float f32x4;
typedef __attribute__((ext_vector_type(4))) unsigned short us4;
typedef __attribute__((ext_vector_type(8))) unsigned short us8;

__device__ __forceinline__ unsigned short f2bf(float f) {
    unsigned u = __float_as_uint(f);
    u += 0x7fffu + ((u >> 16) & 1u);     // round-to-nearest-even
    return (unsigned short)(u >> 16);
}
__device__ __forceinline__ float bf2f(unsigned short v) {
    return __uint_as_float((unsigned)v << 16);
}

// ---------------------------------------------------------------------------
// Kernel 1: 5x5 separable Gaussian blur -> zero-padded channels-last bf16
//   xbt[b][y=h+PD][x=w+PD][c].  (unchanged from R5/R7)
// ---------------------------------------------------------------------------
__global__ __launch_bounds__(256) void blur_t_kernel(const float* __restrict__ x,
                                                     const float* __restrict__ sigma_p,
                                                     unsigned short* __restrict__ xbt) {
    __shared__ __align__(16) unsigned short vb[16][4][264];   // [c%16][row][col+4]
    const int t   = threadIdx.x;
    const int blk = ((blockIdx.x & 7) << 7) + (blockIdx.x >> 3);   // 1024 blocks, chunk 128
    const int band = blk & 63;
    const int b    = blk >> 6;
    const int h0   = band << 2;

    const float sigma = sigma_p[0];
    const float inv2s2 = 1.0f / (2.0f * sigma * sigma);
    float e[5], s = 0.0f;
#pragma unroll
    for (int i = 0; i < 5; ++i) {
        float d = (float)(i - 2);
        e[i] = expf(-(d * d) * inv2s2);
        s += e[i];
    }
    const float inv_s = 1.0f / s;
    float wn[5];
#pragma unroll
    for (int i = 0; i < 5; ++i) wn[i] = e[i] * inv_s;

    unsigned short* xb_img = xbt + (size_t)b * (HP * WP * CC);

    // ---- halo zeroing ----
    const us8 z8 = {0, 0, 0, 0, 0, 0, 0, 0};
    {
        const int j  = t >> 6;
        const int px = (t >> 2) & 15;
        const int ch = t & 3;
        const int xx = (px < PD) ? px : px + WW;
        *reinterpret_cast<us8*>(xb_img + ((size_t)(h0 + PD + j) * WP + xx) * CC + ch * 8) = z8;
    }
    if (h0 < PD) {
#pragma unroll
        for (int j2 = 0; j2 < 4; ++j2) {
            unsigned short* dst = xb_img + (size_t)(h0 + j2) * WP * CC;
            for (int i = t; i < (WP * CC) / 8; i += 256)
                *reinterpret_cast<us8*>(dst + i * 8) = z8;
        }
    }
    if (h0 + 4 > HH - PD) {
#pragma unroll
        for (int j2 = 0; j2 < 4; ++j2) {
            unsigned short* dst = xb_img + (size_t)(h0 + j2 + 2 * PD) * WP * CC;
            for (int i = t; i < (WP * CC) / 8; i += 256)
                *reinterpret_cast<us8*>(dst + i * 8) = z8;
        }
    }

    const int g  = t & 63;
    const int cs = t >> 6;

#pragma unroll
    for (int pass = 0; pass < 2; ++pass) {
        if (pass) __syncthreads();

        {
            const int c15 = t >> 4;
            const int j   = (t >> 2) & 3;
            const int e_  = t & 3;
            const int idx = (e_ < 2) ? (2 + e_) : (258 + e_);
            vb[c15][j][idx] = 0;
        }

#pragma unroll
        for (int it = 0; it < 4; ++it) {
            const int c = (pass << 4) + (it << 2) + cs;
            const float* xc = x + ((size_t)(b * CC + c) * HH) * WW + 4 * g;
            float4 v[8];
#pragma unroll
            for (int k = 0; k < 8; ++k) {
                const int r = h0 - 2 + k;
                v[k] = (r >= 0 && r < HH) ? *reinterpret_cast<const float4*>(xc + r * WW)
                                          : make_float4(0.f, 0.f, 0.f, 0.f);
            }
#pragma unroll
            for (int j = 0; j < 4; ++j) {
                float4 a = make_float4(0.f, 0.f, 0.f, 0.f);
#pragma unroll
                for (int i = 0; i < 5; ++i) {
                    a.x = fmaf(wn[i], v[j + i].x, a.x);
                    a.y = fmaf(wn[i], v[j + i].y, a.y);
                    a.z = fmaf(wn[i], v[j + i].z, a.z);
                    a.w = fmaf(wn[i], v[j + i].w, a.w);
                }
                us4 bv;
                bv[0] = f2bf(a.x); bv[1] = f2bf(a.y);
                bv[2] = f2bf(a.z); bv[3] = f2bf(a.w);
                *reinterpret_cast<us4*>(&vb[c & 15][j][4 + 4 * g]) = bv;
            }
        }
        __syncthreads();

        const int c15 = t & 15;
        const int c   = (pass << 4) + c15;
        const int T   = t >> 4;
#pragma unroll
        for (int j = 0; j < 4; ++j) {
            us4 ch[6];
#pragma unroll
            for (int k = 0; k < 6; ++k)
                ch[k] = *reinterpret_cast<const us4*>(&vb[c15][j][16 * T + 4 * k]);
            float val[24];
#pragma unroll
            for (int q = 0; q < 24; ++q) val[q] = bf2f(ch[q >> 2][q & 3]);
            unsigned short* ob = xb_img + ((size_t)(h0 + PD + j) * WP + PD + 16 * T) * CC + c;
#pragma unroll
            for (int d = 0; d < 16; ++d) {
                float a = 0.0f;
#pragma unroll
                for (int i = 0; i < 5; ++i) a = fmaf(wn[i], val[d + 2 + i], a);
                ob[d * CC] = f2bf(a);
            }
        }
    }
}

// ---------------------------------------------------------------------------
// Kernel 2: corner table (SORTED by image offset => row-major locality) +
// pre-scaled B fragments. (unchanged from R6)
// ---------------------------------------------------------------------------
__global__ void wtrans_kernel(const float* __restrict__ wgt,
                              const float* __restrict__ sigma_p,
                              int* __restrict__ meta,
                              unsigned short* __restrict__ wb2) {
    __shared__ int   s_tap[36];
    __shared__ float s_w[36];
    __shared__ int   s_soff[36];
    __shared__ int   s_n;
    const int t = threadIdx.x;

    if (t == 0) {
        const float UY[9] = {-0.70710678f, -1.0f, -0.70710678f, 0.0f, 0.0f, 0.0f,
                              0.70710678f,  1.0f,  0.70710678f};
        const float UX[9] = {-0.70710678f, 0.0f, 0.70710678f, -1.0f, 0.0f, 1.0f,
                             -0.70710678f, 0.0f, 0.70710678f};
        const int KYI[9] = {-1, -1, -1, 0, 0, 0, 1, 1, 1};
        const int KXI[9] = {-1, 0, 1, -1, 0, 1, -1, 0, 1};
        const float s6 = sigma_p[0] * 6.0f;
        int n = 0;
        for (int s_ = 0; s_ < 9; ++s_) {
            float offy = UY[s_] * s6, offx = UX[s_] * s6;
            float fy = floorf(offy), fx = floorf(offx);
            float ty = offy - fy,    tx = offx - fx;
            int sy = KYI[s_] + (int)fy;
            int sx = KXI[s_] + (int)fx;
            float wy[2] = {1.0f - ty, ty};
            float wx[2] = {1.0f - tx, tx};
            for (int dy = 0; dy < 2; ++dy)
                for (int dx = 0; dx < 2; ++dx) {
                    float wc = wy[dy] * wx[dx];
                    if (wc != 0.0f) {
                        s_tap[n]  = s_;
                        s_w[n]    = wc;
                        s_soff[n] = ((sy + dy) * WP + (sx + dx)) * CC;
                        ++n;
                    }
                }
        }
        // insertion sort by soff (== row-major (Sy,Sx) order)
        for (int i = 1; i < n; ++i) {
            int ks = s_soff[i]; int kt = s_tap[i]; float kw = s_w[i];
            int j = i - 1;
            while (j >= 0 && s_soff[j] > ks) {
                s_soff[j + 1] = s_soff[j]; s_tap[j + 1] = s_tap[j]; s_w[j + 1] = s_w[j];
                --j;
            }
            s_soff[j + 1] = ks; s_tap[j + 1] = kt; s_w[j + 1] = kw;
        }
        if (blockIdx.x == 0) {
            meta[0] = n;
            for (int i = 0; i < n; ++i) meta[1 + i] = s_soff[i];
        }
        s_n = n;
    }
    __syncthreads();

    const int e = blockIdx.x;
    if (e >= s_n) return;
    for (int i = t; i < 1024; i += 256) {
        int j  = i & 7;
        int l  = (i >> 3) & 63;
        int nh = (i >> 9) & 1;
        int o  = nh * 16 + (l & 15);
        int c  = ((l >> 4) << 3) + j;
        wb2[e * 1024 + i] = f2bf(s_w[e] * wgt[(o * CC + c) * 9 + s_tap[e]]);
    }
}

// ---------------------------------------------------------------------------
// Kernel 3: pure-MFMA mix with MANUAL DEPTH-1 PIPELINE (ping-pong A buffers).
// Entry e+1's 8 A-loads are issued BEFORE entry e's 16 MFMAs, so the compiler
// emits counted vmcnt and the loads stay in flight across the MFMA cluster.
// Register cost is fixed by construction (A0+A1 = 64 VGPR) -> no spill at
// launch_bounds(512,4), unlike R8's full unroll at (512,6).
// Block = 8 waves = 4 rows x 2 x-segs; all B entries staged in LDS.
// ---------------------------------------------------------------------------
__global__ __launch_bounds__(512, 4) void mix6_kernel(const unsigned short* __restrict__ xbt,
                                                      const int* __restrict__ meta,
                                                      const unsigned short* __restrict__ wb2,
                                                      float* __restrict__ out) {
    __shared__ us8 bs8[NEMAX * 128];         // up to 72 KB
    const int t    = threadIdx.x;
    const int lane = t & 63;
    const int wv   = t >> 6;                 // 0..7
    const int blk  = ((blockIdx.x & 7) << 7) + (blockIdx.x >> 3);  // 1024 blocks, chunk 128
    const int b    = blk >> 6;
    const int h    = ((blk & 63) << 2) + (wv >> 1);
    const int xseg = (wv & 1) << 7;          // 0 or 128
    const int mrow = lane & 15;
    const int c0   = (lane >> 4) << 3;
    const int ncorn = meta[0];

    // stage all B entries into LDS
    for (int i = t; i < ncorn * 128; i += 512)
        bs8[i] = reinterpret_cast<const us8*>(wb2)[i];
    __syncthreads();

    const unsigned short* rowp = xbt + ((size_t)(b * HP + h + PD) * WP + PD) * CC;
    const int loff = (xseg + mrow) * CC + c0;
    const unsigned short* bsp = reinterpret_cast<const unsigned short*>(bs8);

    f32x4 acc[8][2];
#pragma unroll
    for (int tt = 0; tt < 8; ++tt) {
        acc[tt][0] = (f32x4){0.f, 0.f, 0.f, 0.f};
        acc[tt][1] = (f32x4){0.f, 0.f, 0.f, 0.f};
    }

    bf16x8 A0[8], A1[8];
    {   // preload entry 0
        const unsigned short* p0 = rowp + meta[1] + loff;
#pragma unroll
        for (int tt = 0; tt < 8; ++tt)
            A0[tt] = *reinterpret_cast<const bf16x8*>(p0 + tt * 512);
    }

    int e = 0;
    while (true) {
        // ---- entry e in A0; prefetch e+1 into A1 ----
        if (e + 1 < ncorn) {
            const unsigned short* pn = rowp + meta[2 + e] + loff;
#pragma unroll
            for (int tt = 0; tt < 8; ++tt)
                A1[tt] = *reinterpret_cast<const bf16x8*>(pn + tt * 512);
        }
        {
            const bf16x8 b0 = *reinterpret_cast<const bf16x8*>(bsp + (e * 128 + lane) * 8);
            const bf16x8 b1 = *reinterpret_cast<const bf16x8*>(bsp + (e * 128 + 64 + lane) * 8);
#pragma unroll
            for (int tt = 0; tt < 8; ++tt) {
                acc[tt][0] = __builtin_amdgcn_mfma_f32_16x16x32_bf16(A0[tt], b0, acc[tt][0], 0, 0, 0);
                acc[tt][1] = __builtin_amdgcn_mfma_f32_16x16x32_bf16(A0[tt], b1, acc[tt][1], 0, 0, 0);
            }
        }
        if (++e >= ncorn) break;

        // ---- entry e in A1; prefetch e+1 into A0 ----
        if (e + 1 < ncorn) {
            const unsigned short* pn = rowp + meta[2 + e] + loff;
#pragma unroll
            for (int tt = 0; tt < 8; ++tt)
                A0[tt] = *reinterpret_cast<const bf16x8*>(pn + tt * 512);
        }
        {
            const bf16x8 b0 = *reinterpret_cast<const bf16x8*>(bsp + (e * 128 + lane) * 8);
            const bf16x8 b1 = *reinterpret_cast<const bf16x8*>(bsp + (e * 128 + 64 + lane) * 8);
#pragma unroll
            for (int tt = 0; tt < 8; ++tt) {
                acc[tt][0] = __builtin_amdgcn_mfma_f32_16x16x32_bf16(A1[tt], b0, acc[tt][0], 0, 0, 0);
                acc[tt][1] = __builtin_amdgcn_mfma_f32_16x16x32_bf16(A1[tt], b1, acc[tt][1], 0, 0, 0);
            }
        }
        if (++e >= ncorn) break;
    }

    // D: out channel = lane&15 (+16 for acc1), pixel = xseg + tt*16 + (lane>>4)*4 + j
    const int prow = (lane >> 4) << 2;
    float* op0 = out + ((size_t)b * OO + (lane & 15)) * HW + (size_t)h * WW + xseg + prow;
#pragma unroll
    for (int tt = 0; tt < 8; ++tt) {
        *reinterpret_cast<f32x4*>(op0 + tt * 16) = acc[tt][0];
        *reinterpret_cast<f32x4*>(op0 + tt * 16 + (size_t)16 * HW) = acc[tt][1];
    }
}

// ---------------------------------------------------------------------------
extern "C" void kernel_launch(void* const* d_in, const int* in_sizes, int n_in,
                              void* d_out, int out_size, void* d_ws, size_t ws_size,
                              hipStream_t stream) {
    const float* x     = (const float*)d_in[0];
    const float* sigma = (const float*)d_in[1];
    const float* wgt   = (const float*)d_in[2];
    float* out = (float*)d_out;

    // ws layout: [ meta: 64 ints ][ wb2: 36*1024 bf16 ] (128 KB reserved)
    //            [ xbt: BB*HP*WP*CC bf16 padded image ]
    int* meta           = (int*)d_ws;
    unsigned short* wb2 = (unsigned short*)((char*)d_ws + 256);
    unsigned short* xbt = (unsigned short*)((char*)d_ws + 131072);

    wtrans_kernel<<<36, 256, 0, stream>>>(wgt, sigma, meta, wb2);
    blur_t_kernel<<<BB * 64, 256, 0, stream>>>(x, sigma, xbt);
    mix6_kernel<<<BB * 64, 512, 0, stream>>>(xbt, meta, wb2, out);
}

// Round 10
// 185.792 us; speedup vs baseline: 1.9733x; 1.7315x over previous
//
#include <hip/hip_runtime.h>
#include <math.h>

#define BB 16
#define CC 32
#define OO 32
#define HH 256
#define WW 256
#define HW (HH * WW)
#define PD 8
#define HP (HH + 2 * PD)      // 272
#define WP (WW + 2 * PD)      // 272
#define NEMAX 36

typedef __attribute__((ext_vector_type(8))) short bf16x8;
typedef __attribute__((ext_vector_type(4))) float f32x4;
typedef __attribute__((ext_vector_type(4))) unsigned short us4;
typedef __attribute__((ext_vector_type(8))) unsigned short us8;

__device__ __forceinline__ unsigned short f2bf(float f) {
    unsigned u = __float_as_uint(f);
    u += 0x7fffu + ((u >> 16) & 1u);     // round-to-nearest-even
    return (unsigned short)(u >> 16);
}
__device__ __forceinline__ float bf2f(unsigned short v) {
    return __uint_as_float((unsigned)v << 16);
}

// ---------------------------------------------------------------------------
// Kernel 1: 5x5 separable Gaussian blur -> zero-padded channels-last bf16
//   xbt[b][y=h+PD][x=w+PD][c].  (unchanged from R5/R7)
// ---------------------------------------------------------------------------
__global__ __launch_bounds__(256) void blur_t_kernel(const float* __restrict__ x,
                                                     const float* __restrict__ sigma_p,
                                                     unsigned short* __restrict__ xbt) {
    __shared__ __align__(16) unsigned short vb[16][4][264];   // [c%16][row][col+4]
    const int t   = threadIdx.x;
    const int blk = ((blockIdx.x & 7) << 7) + (blockIdx.x >> 3);   // 1024 blocks, chunk 128
    const int band = blk & 63;
    const int b    = blk >> 6;
    const int h0   = band << 2;

    const float sigma = sigma_p[0];
    const float inv2s2 = 1.0f / (2.0f * sigma * sigma);
    float e[5], s = 0.0f;
#pragma unroll
    for (int i = 0; i < 5; ++i) {
        float d = (float)(i - 2);
        e[i] = expf(-(d * d) * inv2s2);
        s += e[i];
    }
    const float inv_s = 1.0f / s;
    float wn[5];
#pragma unroll
    for (int i = 0; i < 5; ++i) wn[i] = e[i] * inv_s;

    unsigned short* xb_img = xbt + (size_t)b * (HP * WP * CC);

    // ---- halo zeroing ----
    const us8 z8 = {0, 0, 0, 0, 0, 0, 0, 0};
    {
        const int j  = t >> 6;
        const int px = (t >> 2) & 15;
        const int ch = t & 3;
        const int xx = (px < PD) ? px : px + WW;
        *reinterpret_cast<us8*>(xb_img + ((size_t)(h0 + PD + j) * WP + xx) * CC + ch * 8) = z8;
    }
    if (h0 < PD) {
#pragma unroll
        for (int j2 = 0; j2 < 4; ++j2) {
            unsigned short* dst = xb_img + (size_t)(h0 + j2) * WP * CC;
            for (int i = t; i < (WP * CC) / 8; i += 256)
                *reinterpret_cast<us8*>(dst + i * 8) = z8;
        }
    }
    if (h0 + 4 > HH - PD) {
#pragma unroll
        for (int j2 = 0; j2 < 4; ++j2) {
            unsigned short* dst = xb_img + (size_t)(h0 + j2 + 2 * PD) * WP * CC;
            for (int i = t; i < (WP * CC) / 8; i += 256)
                *reinterpret_cast<us8*>(dst + i * 8) = z8;
        }
    }

    const int g  = t & 63;
    const int cs = t >> 6;

#pragma unroll
    for (int pass = 0; pass < 2; ++pass) {
        if (pass) __syncthreads();

        {
            const int c15 = t >> 4;
            const int j   = (t >> 2) & 3;
            const int e_  = t & 3;
            const int idx = (e_ < 2) ? (2 + e_) : (258 + e_);
            vb[c15][j][idx] = 0;
        }

#pragma unroll
        for (int it = 0; it < 4; ++it) {
            const int c = (pass << 4) + (it << 2) + cs;
            const float* xc = x + ((size_t)(b * CC + c) * HH) * WW + 4 * g;
            float4 v[8];
#pragma unroll
            for (int k = 0; k < 8; ++k) {
                const int r = h0 - 2 + k;
                v[k] = (r >= 0 && r < HH) ? *reinterpret_cast<const float4*>(xc + r * WW)
                                          : make_float4(0.f, 0.f, 0.f, 0.f);
            }
#pragma unroll
            for (int j = 0; j < 4; ++j) {
                float4 a = make_float4(0.f, 0.f, 0.f, 0.f);
#pragma unroll
                for (int i = 0; i < 5; ++i) {
                    a.x = fmaf(wn[i], v[j + i].x, a.x);
                    a.y = fmaf(wn[i], v[j + i].y, a.y);
                    a.z = fmaf(wn[i], v[j + i].z, a.z);
                    a.w = fmaf(wn[i], v[j + i].w, a.w);
                }
                us4 bv;
                bv[0] = f2bf(a.x); bv[1] = f2bf(a.y);
                bv[2] = f2bf(a.z); bv[3] = f2bf(a.w);
                *reinterpret_cast<us4*>(&vb[c & 15][j][4 + 4 * g]) = bv;
            }
        }
        __syncthreads();

        const int c15 = t & 15;
        const int c   = (pass << 4) + c15;
        const int T   = t >> 4;
#pragma unroll
        for (int j = 0; j < 4; ++j) {
            us4 ch[6];
#pragma unroll
            for (int k = 0; k < 6; ++k)
                ch[k] = *reinterpret_cast<const us4*>(&vb[c15][j][16 * T + 4 * k]);
            float val[24];
#pragma unroll
            for (int q = 0; q < 24; ++q) val[q] = bf2f(ch[q >> 2][q & 3]);
            unsigned short* ob = xb_img + ((size_t)(h0 + PD + j) * WP + PD + 16 * T) * CC + c;
#pragma unroll
            for (int d = 0; d < 16; ++d) {
                float a = 0.0f;
#pragma unroll
                for (int i = 0; i < 5; ++i) a = fmaf(wn[i], val[d + 2 + i], a);
                ob[d * CC] = f2bf(a);
            }
        }
    }
}

// ---------------------------------------------------------------------------
// Kernel 2: corner table (SORTED by image offset => row-major locality) +
// pre-scaled B fragments. (unchanged from R6)
// ---------------------------------------------------------------------------
__global__ void wtrans_kernel(const float* __restrict__ wgt,
                              const float* __restrict__ sigma_p,
                              int* __restrict__ meta,
                              unsigned short* __restrict__ wb2) {
    __shared__ int   s_tap[36];
    __shared__ float s_w[36];
    __shared__ int   s_soff[36];
    __shared__ int   s_n;
    const int t = threadIdx.x;

    if (t == 0) {
        const float UY[9] = {-0.70710678f, -1.0f, -0.70710678f, 0.0f, 0.0f, 0.0f,
                              0.70710678f,  1.0f,  0.70710678f};
        const float UX[9] = {-0.70710678f, 0.0f, 0.70710678f, -1.0f, 0.0f, 1.0f,
                             -0.70710678f, 0.0f, 0.70710678f};
        const int KYI[9] = {-1, -1, -1, 0, 0, 0, 1, 1, 1};
        const int KXI[9] = {-1, 0, 1, -1, 0, 1, -1, 0, 1};
        const float s6 = sigma_p[0] * 6.0f;
        int n = 0;
        for (int s_ = 0; s_ < 9; ++s_) {
            float offy = UY[s_] * s6, offx = UX[s_] * s6;
            float fy = floorf(offy), fx = floorf(offx);
            float ty = offy - fy,    tx = offx - fx;
            int sy = KYI[s_] + (int)fy;
            int sx = KXI[s_] + (int)fx;
            float wy[2] = {1.0f - ty, ty};
            float wx[2] = {1.0f - tx, tx};
            for (int dy = 0; dy < 2; ++dy)
                for (int dx = 0; dx < 2; ++dx) {
                    float wc = wy[dy] * wx[dx];
                    if (wc != 0.0f) {
                        s_tap[n]  = s_;
                        s_w[n]    = wc;
                        s_soff[n] = ((sy + dy) * WP + (sx + dx)) * CC;
                        ++n;
                    }
                }
        }
        // insertion sort by soff (== row-major (Sy,Sx) order)
        for (int i = 1; i < n; ++i) {
            int ks = s_soff[i]; int kt = s_tap[i]; float kw = s_w[i];
            int j = i - 1;
            while (j >= 0 && s_soff[j] > ks) {
                s_soff[j + 1] = s_soff[j]; s_tap[j + 1] = s_tap[j]; s_w[j + 1] = s_w[j];
                --j;
            }
            s_soff[j + 1] = ks; s_tap[j + 1] = kt; s_w[j + 1] = kw;
        }
        if (blockIdx.x == 0) {
            meta[0] = n;
            for (int i = 0; i < n; ++i) meta[1 + i] = s_soff[i];
        }
        s_n = n;
    }
    __syncthreads();

    const int e = blockIdx.x;
    if (e >= s_n) return;
    for (int i = t; i < 1024; i += 256) {
        int j  = i & 7;
        int l  = (i >> 3) & 63;
        int nh = (i >> 9) & 1;
        int o  = nh * 16 + (l & 15);
        int c  = ((l >> 4) << 3) + j;
        wb2[e * 1024 + i] = f2bf(s_w[e] * wgt[(o * CC + c) * 9 + s_tap[e]]);
    }
}

// ---------------------------------------------------------------------------
// Kernel 3: pure-MFMA mix with (a) WAVE DE-PHASING (each wave starts the
// order-independent entry sum at a rotated index -> waves on a SIMD alternate
// load-wait/MFMA instead of stalling together) and (b) HALF-ENTRY GROUP
// PIPELINE (G0/G1 of 4 tiles: issue G1(e) -> MFMA G0(e) -> issue G0(e+1) ->
// MFMA G1(e)). Max live A = 32 VGPR, same footprint as R7 -> no spill at
// (512,4) (R8/R9 lesson: acc64+A64 > 128-reg budget forces scratch).
// soff s_loads prefetched 2 entries ahead (off critical path).
// ---------------------------------------------------------------------------
__global__ __launch_bounds__(512, 4) void mix7_kernel(const unsigned short* __restrict__ xbt,
                                                      const int* __restrict__ meta,
                                                      const unsigned short* __restrict__ wb2,
                                                      float* __restrict__ out) {
    __shared__ us8 bs8[NEMAX * 128];         // up to 72 KB
    const int t    = threadIdx.x;
    const int lane = t & 63;
    const int wv   = t >> 6;                 // 0..7
    const int blk  = ((blockIdx.x & 7) << 7) + (blockIdx.x >> 3);  // 1024 blocks, chunk 128
    const int b    = blk >> 6;
    const int h    = ((blk & 63) << 2) + (wv >> 1);
    const int xseg = (wv & 1) << 7;          // 0 or 128
    const int mrow = lane & 15;
    const int c0   = (lane >> 4) << 3;
    const int ncorn = meta[0];

    // stage all B entries into LDS
    for (int i = t; i < ncorn * 128; i += 512)
        bs8[i] = reinterpret_cast<const us8*>(wb2)[i];
    __syncthreads();

    const unsigned short* rowp = xbt + ((size_t)(b * HP + h + PD) * WP + PD) * CC;
    const int loff = (xseg + mrow) * CC + c0;
    const unsigned short* bsp = reinterpret_cast<const unsigned short*>(bs8);

    f32x4 acc[8][2];
#pragma unroll
    for (int tt = 0; tt < 8; ++tt) {
        acc[tt][0] = (f32x4){0.f, 0.f, 0.f, 0.f};
        acc[tt][1] = (f32x4){0.f, 0.f, 0.f, 0.f};
    }

    // wave de-phasing: rotated start entry (sum is order-independent; order
    // is fixed per pixel -> deterministic output)
    int er0 = (wv * 5) % ncorn;
    int er1 = (er0 + 1 == ncorn) ? 0 : er0 + 1;
    int soff1 = meta[1 + er1];

    bf16x8 G0[4], G1[4];
    const unsigned short* pe0 = rowp + meta[1 + er0] + loff;
#pragma unroll
    for (int tt = 0; tt < 4; ++tt)
        G0[tt] = *reinterpret_cast<const bf16x8*>(pe0 + tt * 512);

    for (int i = 0; i < ncorn; ++i) {
        // prefetch soff two entries ahead (s_load hidden under this iter)
        const int er2 = (er1 + 1 == ncorn) ? 0 : er1 + 1;
        const int soff2 = meta[1 + er2];
        const unsigned short* pe1 = rowp + soff1 + loff;

        // issue G1(cur) loads — in flight across G0's MFMAs
#pragma unroll
        for (int tt = 0; tt < 4; ++tt)
            G1[tt] = *reinterpret_cast<const bf16x8*>(pe0 + (4 + tt) * 512);

        const bf16x8 b0 = *reinterpret_cast<const bf16x8*>(bsp + (er0 * 128 + lane) * 8);
        const bf16x8 b1 = *reinterpret_cast<const bf16x8*>(bsp + (er0 * 128 + 64 + lane) * 8);

#pragma unroll
        for (int tt = 0; tt < 4; ++tt) {
            acc[tt][0] = __builtin_amdgcn_mfma_f32_16x16x32_bf16(G0[tt], b0, acc[tt][0], 0, 0, 0);
            acc[tt][1] = __builtin_amdgcn_mfma_f32_16x16x32_bf16(G0[tt], b1, acc[tt][1], 0, 0, 0);
        }

        // issue G0(next) loads — in flight across G1's MFMAs (last iter: wraps
        // to a valid entry; 4 extra loads, harmless)
#pragma unroll
        for (int tt = 0; tt < 4; ++tt)
            G0[tt] = *reinterpret_cast<const bf16x8*>(pe1 + tt * 512);

#pragma unroll
        for (int tt = 0; tt < 4; ++tt) {
            acc[4 + tt][0] = __builtin_amdgcn_mfma_f32_16x16x32_bf16(G1[tt], b0, acc[4 + tt][0], 0, 0, 0);
            acc[4 + tt][1] = __builtin_amdgcn_mfma_f32_16x16x32_bf16(G1[tt], b1, acc[4 + tt][1], 0, 0, 0);
        }

        er0 = er1; er1 = er2; soff1 = soff2; pe0 = pe1;
    }

    // D: out channel = lane&15 (+16 for acc1), pixel = xseg + tt*16 + (lane>>4)*4 + j
    const int prow = (lane >> 4) << 2;
    float* op0 = out + ((size_t)b * OO + (lane & 15)) * HW + (size_t)h * WW + xseg + prow;
#pragma unroll
    for (int tt = 0; tt < 8; ++tt) {
        *reinterpret_cast<f32x4*>(op0 + tt * 16) = acc[tt][0];
        *reinterpret_cast<f32x4*>(op0 + tt * 16 + (size_t)16 * HW) = acc[tt][1];
    }
}

// ---------------------------------------------------------------------------
extern "C" void kernel_launch(void* const* d_in, const int* in_sizes, int n_in,
                              void* d_out, int out_size, void* d_ws, size_t ws_size,
                              hipStream_t stream) {
    const float* x     = (const float*)d_in[0];
    const float* sigma = (const float*)d_in[1];
    const float* wgt   = (const float*)d_in[2];
    float* out = (float*)d_out;

    // ws layout: [ meta: 64 ints ][ wb2: 36*1024 bf16 ] (128 KB reserved)
    //            [ xbt: BB*HP*WP*CC bf16 padded image ]
    int* meta           = (int*)d_ws;
    unsigned short* wb2 = (unsigned short*)((char*)d_ws + 256);
    unsigned short* xbt = (unsigned short*)((char*)d_ws + 131072);

    wtrans_kernel<<<36, 256, 0, stream>>>(wgt, sigma, meta, wb2);
    blur_t_kernel<<<BB * 64, 256, 0, stream>>>(x, sigma, xbt);
    mix7_kernel<<<BB * 64, 512, 0, stream>>>(xbt, meta, wb2, out);
}

// Round 11
// 162.244 us; speedup vs baseline: 2.2597x; 1.1451x over previous
//
#include <hip/hip_runtime.h>
#include <math.h>

#define BB 16
#define CC 32
#define OO 32
#define HH 256
#define WW 256
#define HW (HH * WW)
#define PD 8
#define HP (HH + 2 * PD)      // 272
#define WP (WW + 2 * PD)      // 272
#define NEMAX 36

// mix8 window geometry: block = 16 rows x 64 px; shifts |Sy|,|Sx| <= 7
#define WROWS 30              // 16 + 2*7
#define WCOLS 80              // 64 + 2*7, rounded to 80
#define PLANE (WROWS * WCOLS + 1)   // 16B units per channel-plane; +1 => plane stride ≡1 (mod 8) banks

typedef __attribute__((ext_vector_type(8))) short bf16x8;
typedef __attribute__((ext_vector_type(4))) float f32x4;
typedef __attribute__((ext_vector_type(4))) unsigned short us4;
typedef __attribute__((ext_vector_type(8))) unsigned short us8;

__device__ __forceinline__ unsigned short f2bf(float f) {
    unsigned u = __float_as_uint(f);
    u += 0x7fffu + ((u >> 16) & 1u);     // round-to-nearest-even
    return (unsigned short)(u >> 16);
}
__device__ __forceinline__ float bf2f(unsigned short v) {
    return __uint_as_float((unsigned)v << 16);
}

// ---------------------------------------------------------------------------
// Kernel 1: 5x5 separable Gaussian blur -> zero-padded channels-last bf16
//   xbt[b][y=h+PD][x=w+PD][c].  (unchanged from R5/R7)
// ---------------------------------------------------------------------------
__global__ __launch_bounds__(256) void blur_t_kernel(const float* __restrict__ x,
                                                     const float* __restrict__ sigma_p,
                                                     unsigned short* __restrict__ xbt) {
    __shared__ __align__(16) unsigned short vb[16][4][264];   // [c%16][row][col+4]
    const int t   = threadIdx.x;
    const int blk = ((blockIdx.x & 7) << 7) + (blockIdx.x >> 3);   // 1024 blocks, chunk 128
    const int band = blk & 63;
    const int b    = blk >> 6;
    const int h0   = band << 2;

    const float sigma = sigma_p[0];
    const float inv2s2 = 1.0f / (2.0f * sigma * sigma);
    float e[5], s = 0.0f;
#pragma unroll
    for (int i = 0; i < 5; ++i) {
        float d = (float)(i - 2);
        e[i] = expf(-(d * d) * inv2s2);
        s += e[i];
    }
    const float inv_s = 1.0f / s;
    float wn[5];
#pragma unroll
    for (int i = 0; i < 5; ++i) wn[i] = e[i] * inv_s;

    unsigned short* xb_img = xbt + (size_t)b * (HP * WP * CC);

    // ---- halo zeroing ----
    const us8 z8 = {0, 0, 0, 0, 0, 0, 0, 0};
    {
        const int j  = t >> 6;
        const int px = (t >> 2) & 15;
        const int ch = t & 3;
        const int xx = (px < PD) ? px : px + WW;
        *reinterpret_cast<us8*>(xb_img + ((size_t)(h0 + PD + j) * WP + xx) * CC + ch * 8) = z8;
    }
    if (h0 < PD) {
#pragma unroll
        for (int j2 = 0; j2 < 4; ++j2) {
            unsigned short* dst = xb_img + (size_t)(h0 + j2) * WP * CC;
            for (int i = t; i < (WP * CC) / 8; i += 256)
                *reinterpret_cast<us8*>(dst + i * 8) = z8;
        }
    }
    if (h0 + 4 > HH - PD) {
#pragma unroll
        for (int j2 = 0; j2 < 4; ++j2) {
            unsigned short* dst = xb_img + (size_t)(h0 + j2 + 2 * PD) * WP * CC;
            for (int i = t; i < (WP * CC) / 8; i += 256)
                *reinterpret_cast<us8*>(dst + i * 8) = z8;
        }
    }

    const int g  = t & 63;
    const int cs = t >> 6;

#pragma unroll
    for (int pass = 0; pass < 2; ++pass) {
        if (pass) __syncthreads();

        {
            const int c15 = t >> 4;
            const int j   = (t >> 2) & 3;
            const int e_  = t & 3;
            const int idx = (e_ < 2) ? (2 + e_) : (258 + e_);
            vb[c15][j][idx] = 0;
        }

#pragma unroll
        for (int it = 0; it < 4; ++it) {
            const int c = (pass << 4) + (it << 2) + cs;
            const float* xc = x + ((size_t)(b * CC + c) * HH) * WW + 4 * g;
            float4 v[8];
#pragma unroll
            for (int k = 0; k < 8; ++k) {
                const int r = h0 - 2 + k;
                v[k] = (r >= 0 && r < HH) ? *reinterpret_cast<const float4*>(xc + r * WW)
                                          : make_float4(0.f, 0.f, 0.f, 0.f);
            }
#pragma unroll
            for (int j = 0; j < 4; ++j) {
                float4 a = make_float4(0.f, 0.f, 0.f, 0.f);
#pragma unroll
                for (int i = 0; i < 5; ++i) {
                    a.x = fmaf(wn[i], v[j + i].x, a.x);
                    a.y = fmaf(wn[i], v[j + i].y, a.y);
                    a.z = fmaf(wn[i], v[j + i].z, a.z);
                    a.w = fmaf(wn[i], v[j + i].w, a.w);
                }
                us4 bv;
                bv[0] = f2bf(a.x); bv[1] = f2bf(a.y);
                bv[2] = f2bf(a.z); bv[3] = f2bf(a.w);
                *reinterpret_cast<us4*>(&vb[c & 15][j][4 + 4 * g]) = bv;
            }
        }
        __syncthreads();

        const int c15 = t & 15;
        const int c   = (pass << 4) + c15;
        const int T   = t >> 4;
#pragma unroll
        for (int j = 0; j < 4; ++j) {
            us4 ch[6];
#pragma unroll
            for (int k = 0; k < 6; ++k)
                ch[k] = *reinterpret_cast<const us4*>(&vb[c15][j][16 * T + 4 * k]);
            float val[24];
#pragma unroll
            for (int q = 0; q < 24; ++q) val[q] = bf2f(ch[q >> 2][q & 3]);
            unsigned short* ob = xb_img + ((size_t)(h0 + PD + j) * WP + PD + 16 * T) * CC + c;
#pragma unroll
            for (int d = 0; d < 16; ++d) {
                float a = 0.0f;
#pragma unroll
                for (int i = 0; i < 5; ++i) a = fmaf(wn[i], val[d + 2 + i], a);
                ob[d * CC] = f2bf(a);
            }
        }
    }
}

// ---------------------------------------------------------------------------
// Kernel 2: corner table (sorted by image offset) + pre-scaled B fragments.
// Adds: meta[37+e] = window-relative offset (Sy+7)*WCOLS + (Sx+8) for the
// LDS-staged mix path; meta[74] = 1 if all shifts fit |Sy|,|Sx| <= 7.
// ---------------------------------------------------------------------------
__global__ void wtrans_kernel(const float* __restrict__ wgt,
                              const float* __restrict__ sigma_p,
                              int* __restrict__ meta,
                              unsigned short* __restrict__ wb2) {
    __shared__ int   s_tap[36];
    __shared__ float s_w[36];
    __shared__ int   s_soff[36];
    __shared__ int   s_wrel[36];
    __shared__ int   s_n;
    const int t = threadIdx.x;

    if (t == 0) {
        const float UY[9] = {-0.70710678f, -1.0f, -0.70710678f, 0.0f, 0.0f, 0.0f,
                              0.70710678f,  1.0f,  0.70710678f};
        const float UX[9] = {-0.70710678f, 0.0f, 0.70710678f, -1.0f, 0.0f, 1.0f,
                             -0.70710678f, 0.0f, 0.70710678f};
        const int KYI[9] = {-1, -1, -1, 0, 0, 0, 1, 1, 1};
        const int KXI[9] = {-1, 0, 1, -1, 0, 1, -1, 0, 1};
        const float s6 = sigma_p[0] * 6.0f;
        int n = 0, ok = 1;
        for (int s_ = 0; s_ < 9; ++s_) {
            float offy = UY[s_] * s6, offx = UX[s_] * s6;
            float fy = floorf(offy), fx = floorf(offx);
            float ty = offy - fy,    tx = offx - fx;
            int sy = KYI[s_] + (int)fy;
            int sx = KXI[s_] + (int)fx;
            float wy[2] = {1.0f - ty, ty};
            float wx[2] = {1.0f - tx, tx};
            for (int dy = 0; dy < 2; ++dy)
                for (int dx = 0; dx < 2; ++dx) {
                    float wc = wy[dy] * wx[dx];
                    if (wc != 0.0f) {
                        const int syc = sy + dy, sxc = sx + dx;
                        s_tap[n]  = s_;
                        s_w[n]    = wc;
                        s_soff[n] = (syc * WP + sxc) * CC;
                        s_wrel[n] = (syc + 7) * WCOLS + (sxc + 8);
                        if (syc < -7 || syc > 7 || sxc < -7 || sxc > 7) ok = 0;
                        ++n;
                    }
                }
        }
        // insertion sort by soff (== row-major (Sy,Sx) order; wrel co-sorts)
        for (int i = 1; i < n; ++i) {
            int ks = s_soff[i]; int kt = s_tap[i]; float kw = s_w[i]; int kr = s_wrel[i];
            int j = i - 1;
            while (j >= 0 && s_soff[j] > ks) {
                s_soff[j + 1] = s_soff[j]; s_tap[j + 1] = s_tap[j];
                s_w[j + 1] = s_w[j];       s_wrel[j + 1] = s_wrel[j];
                --j;
            }
            s_soff[j + 1] = ks; s_tap[j + 1] = kt; s_w[j + 1] = kw; s_wrel[j + 1] = kr;
        }
        if (blockIdx.x == 0) {
            meta[0] = n;
            for (int i = 0; i < n; ++i) { meta[1 + i] = s_soff[i]; meta[37 + i] = s_wrel[i]; }
            meta[74] = ok;
        }
        s_n = n;
    }
    __syncthreads();

    const int e = blockIdx.x;
    if (e >= s_n) return;
    for (int i = t; i < 1024; i += 256) {
        int j  = i & 7;
        int l  = (i >> 3) & 63;
        int nh = (i >> 9) & 1;
        int o  = nh * 16 + (l & 15);
        int c  = ((l >> 4) << 3) + j;
        wb2[e * 1024 + i] = f2bf(s_w[e] * wgt[(o * CC + c) * 9 + s_tap[e]]);
    }
}

// ---------------------------------------------------------------------------
// Kernel 3: LDS-STAGED stencil GEMM. Block = 16 rows x 64 px (512 thr, 8 wv).
// The 30x80x32c input window (150 KB) is staged into LDS ONCE; all 21 entries
// read A from LDS (R7-R10 analysis: A re-missing L1 21x was the 120us wall).
// Layout: 4 channel-unit planes of [row][px] 16B cells, plane stride
// PLANE = 30*80+1 units (odd -> planes offset by 1 bank-group: <=2-way
// conflicts, free per m136). Per entry: 1 v_add + 8 ds_read_b128 (imm offs)
// + 2 B loads (global, L1-resident 43KB) + 16 MFMA.
// Wave wv owns rows {2wv, 2wv+1} x 4 tiles. Fallback (big sigma): A global.
// ---------------------------------------------------------------------------
__global__ __launch_bounds__(512) void mix8_kernel(const unsigned short* __restrict__ xbt,
                                                   const int* __restrict__ meta,
                                                   const unsigned short* __restrict__ wb2,
                                                   float* __restrict__ out) {
    __shared__ bf16x8 win[4 * PLANE];        // 153,664 B
    const int t    = threadIdx.x;
    const int lane = t & 63;
    const int wv   = t >> 6;                 // 0..7
    const int blk  = ((blockIdx.x & 7) << 7) + (blockIdx.x >> 3);  // 1024 blocks, chunk 128
    const int xs   = blk & 3;
    const int band = (blk >> 2) & 15;
    const int b    = blk >> 6;
    const int h0   = band << 4;
    const int x0   = xs << 6;
    const int mrow = lane & 15;
    const int cu   = lane >> 4;              // channel-unit 0..3
    const int ncorn = meta[0];
    const int ok    = meta[74];

    const unsigned short* img = xbt + (size_t)b * (HP * WP * CC);

    f32x4 acc[8][2];                         // [ri*4+tx][half]
#pragma unroll
    for (int q = 0; q < 8; ++q) {
        acc[q][0] = (f32x4){0.f, 0.f, 0.f, 0.f};
        acc[q][1] = (f32x4){0.f, 0.f, 0.f, 0.f};
    }

    if (ok) {
        // ---- stage window: rows h0-7..h0+22 (padded h0+1..), px x0-8..x0+71 ----
        const unsigned short* gsrc = img + ((size_t)(h0 + 1) * WP + x0) * CC;
        for (int i = t; i < WROWS * WCOLS * 4; i += 512) {
            const int cui = i & 3;
            const int pxl = (i >> 2) % WCOLS;
            const int row = (i >> 2) / WCOLS;
            win[cui * PLANE + row * WCOLS + pxl] =
                *reinterpret_cast<const bf16x8*>(gsrc + ((size_t)row * WP + pxl) * CC + cui * 8);
        }
        __syncthreads();

        const int ubase = cu * PLANE + (wv * 2) * WCOLS + mrow;   // per-lane, loop-invariant
        for (int e = 0; e < ncorn; ++e) {
            const int ewr = meta[37 + e];                          // wave-uniform s_load
            const bf16x8 b0 = *reinterpret_cast<const bf16x8*>(wb2 + ((e * 2 + 0) * 64 + lane) * 8);
            const bf16x8 b1 = *reinterpret_cast<const bf16x8*>(wb2 + ((e * 2 + 1) * 64 + lane) * 8);
            const int abase = ubase + ewr;
#pragma unroll
            for (int ri = 0; ri < 2; ++ri) {
#pragma unroll
                for (int tx = 0; tx < 4; ++tx) {
                    const bf16x8 a = win[abase + ri * WCOLS + tx * 16];  // imm-foldable
                    acc[ri * 4 + tx][0] = __builtin_amdgcn_mfma_f32_16x16x32_bf16(a, b0, acc[ri * 4 + tx][0], 0, 0, 0);
                    acc[ri * 4 + tx][1] = __builtin_amdgcn_mfma_f32_16x16x32_bf16(a, b1, acc[ri * 4 + tx][1], 0, 0, 0);
                }
            }
        }
    } else {
        // generic fallback (any sigma): A straight from global
        const unsigned short* gb = img + ((size_t)(h0 + wv * 2 + PD) * WP + x0 + PD) * CC
                                       + mrow * CC + cu * 8;
        for (int e = 0; e < ncorn; ++e) {
            const int soff = meta[1 + e];
            const bf16x8 b0 = *reinterpret_cast<const bf16x8*>(wb2 + ((e * 2 + 0) * 64 + lane) * 8);
            const bf16x8 b1 = *reinterpret_cast<const bf16x8*>(wb2 + ((e * 2 + 1) * 64 + lane) * 8);
#pragma unroll
            for (int ri = 0; ri < 2; ++ri) {
#pragma unroll
                for (int tx = 0; tx < 4; ++tx) {
                    const bf16x8 a = *reinterpret_cast<const bf16x8*>(
                        gb + soff + ((size_t)ri * WP + tx * 16) * CC);
                    acc[ri * 4 + tx][0] = __builtin_amdgcn_mfma_f32_16x16x32_bf16(a, b0, acc[ri * 4 + tx][0], 0, 0, 0);
                    acc[ri * 4 + tx][1] = __builtin_amdgcn_mfma_f32_16x16x32_bf16(a, b1, acc[ri * 4 + tx][1], 0, 0, 0);
                }
            }
        }
    }

    // D: out channel = lane&15 (+16 for half1), pixel = x0 + tx*16 + (lane>>4)*4 + reg
    const int prow = cu << 2;
    float* op0 = out + ((size_t)b * OO + (lane & 15)) * HW;
#pragma unroll
    for (int ri = 0; ri < 2; ++ri) {
        float* opr = op0 + (size_t)(h0 + wv * 2 + ri) * WW + x0 + prow;
#pragma unroll
        for (int tx = 0; tx < 4; ++tx) {
            *reinterpret_cast<f32x4*>(opr + tx * 16) = acc[ri * 4 + tx][0];
            *reinterpret_cast<f32x4*>(opr + tx * 16 + (size_t)16 * HW) = acc[ri * 4 + tx][1];
        }
    }
}

// ---------------------------------------------------------------------------
extern "C" void kernel_launch(void* const* d_in, const int* in_sizes, int n_in,
                              void* d_out, int out_size, void* d_ws, size_t ws_size,
                              hipStream_t stream) {
    const float* x     = (const float*)d_in[0];
    const float* sigma = (const float*)d_in[1];
    const float* wgt   = (const float*)d_in[2];
    float* out = (float*)d_out;

    // ws layout: [ meta: 128 ints ][ wb2: 36*1024 bf16 ] (128 KB reserved)
    //            [ xbt: BB*HP*WP*CC bf16 padded image ]
    int* meta           = (int*)d_ws;
    unsigned short* wb2 = (unsigned short*)((char*)d_ws + 512);
    unsigned short* xbt = (unsigned short*)((char*)d_ws + 131072);

    wtrans_kernel<<<36, 256, 0, stream>>>(wgt, sigma, meta, wb2);
    blur_t_kernel<<<BB * 64, 256, 0, stream>>>(x, sigma, xbt);
    mix8_kernel<<<BB * 64, 512, 0, stream>>>(xbt, meta, wb2, out);
}

// Round 12
// 156.452 us; speedup vs baseline: 2.3433x; 1.0370x over previous
//
#include <hip/hip_runtime.h>
#include <math.h>

#define BB 16
#define CC 32
#define OO 32
#define HH 256
#define WW 256
#define HW (HH * WW)
#define PD 8
#define HP (HH + 2 * PD)      // 272
#define WP (WW + 2 * PD)      // 272
#define NEMAX 36

// mix8 window geometry: block = 16 rows x 64 px; shifts |Sy|,|Sx| <= 7
#define WROWS 30              // 16 + 2*7
#define WCOLS 80              // 64 + 2*7, rounded to 80
#define PLANE (WROWS * WCOLS + 1)   // 16B units per channel-plane; +1 => plane stride ≡1 (mod 8) banks

typedef __attribute__((ext_vector_type(8))) short bf16x8;
typedef __attribute__((ext_vector_type(4))) float f32x4;
typedef __attribute__((ext_vector_type(4))) unsigned short us4;
typedef __attribute__((ext_vector_type(8))) unsigned short us8;

__device__ __forceinline__ unsigned short f2bf(float f) {
    unsigned u = __float_as_uint(f);
    u += 0x7fffu + ((u >> 16) & 1u);     // round-to-nearest-even
    return (unsigned short)(u >> 16);
}
__device__ __forceinline__ float bf2f(unsigned short v) {
    return __uint_as_float((unsigned)v << 16);
}

// ---------------------------------------------------------------------------
// Kernel 1: 5x5 separable Gaussian blur -> zero-padded channels-last bf16
//   xbt[b][y=h+PD][x=w+PD][c].
// R12: (a) x loads are NONTEMPORAL (single-use stream; keep L3 for xbt/out —
// R11 showed mix8's streaming evicted x and blur went 62->107us);
// (b) phase 2 rewritten: thread = 8ch x 4px -> 4 us8 coalesced stores per j
// (was 128 scalar 2B stores/thread). Same arithmetic, same tap order.
// ---------------------------------------------------------------------------
__global__ __launch_bounds__(256) void blur_t_kernel(const float* __restrict__ x,
                                                     const float* __restrict__ sigma_p,
                                                     unsigned short* __restrict__ xbt) {
    __shared__ __align__(16) unsigned short vb[16][4][264];   // [c%16][row][col+4]
    const int t   = threadIdx.x;
    const int blk = ((blockIdx.x & 7) << 7) + (blockIdx.x >> 3);   // 1024 blocks, chunk 128
    const int band = blk & 63;
    const int b    = blk >> 6;
    const int h0   = band << 2;

    const float sigma = sigma_p[0];
    const float inv2s2 = 1.0f / (2.0f * sigma * sigma);
    float e[5], s = 0.0f;
#pragma unroll
    for (int i = 0; i < 5; ++i) {
        float d = (float)(i - 2);
        e[i] = expf(-(d * d) * inv2s2);
        s += e[i];
    }
    const float inv_s = 1.0f / s;
    float wn[5];
#pragma unroll
    for (int i = 0; i < 5; ++i) wn[i] = e[i] * inv_s;

    unsigned short* xb_img = xbt + (size_t)b * (HP * WP * CC);

    // ---- halo zeroing ----
    const us8 z8 = {0, 0, 0, 0, 0, 0, 0, 0};
    {
        const int j  = t >> 6;
        const int px = (t >> 2) & 15;
        const int ch = t & 3;
        const int xx = (px < PD) ? px : px + WW;
        *reinterpret_cast<us8*>(xb_img + ((size_t)(h0 + PD + j) * WP + xx) * CC + ch * 8) = z8;
    }
    if (h0 < PD) {
#pragma unroll
        for (int j2 = 0; j2 < 4; ++j2) {
            unsigned short* dst = xb_img + (size_t)(h0 + j2) * WP * CC;
            for (int i = t; i < (WP * CC) / 8; i += 256)
                *reinterpret_cast<us8*>(dst + i * 8) = z8;
        }
    }
    if (h0 + 4 > HH - PD) {
#pragma unroll
        for (int j2 = 0; j2 < 4; ++j2) {
            unsigned short* dst = xb_img + (size_t)(h0 + j2 + 2 * PD) * WP * CC;
            for (int i = t; i < (WP * CC) / 8; i += 256)
                *reinterpret_cast<us8*>(dst + i * 8) = z8;
        }
    }

    const int g  = t & 63;
    const int cs = t >> 6;

#pragma unroll
    for (int pass = 0; pass < 2; ++pass) {
        if (pass) __syncthreads();

        {
            const int c15 = t >> 4;
            const int j   = (t >> 2) & 3;
            const int e_  = t & 3;
            const int idx = (e_ < 2) ? (2 + e_) : (258 + e_);
            vb[c15][j][idx] = 0;
        }

        // ---- phase 1: vertical blur over 8 input rows -> 4 outputs ----
#pragma unroll
        for (int it = 0; it < 4; ++it) {
            const int c = (pass << 4) + (it << 2) + cs;
            const float* xc = x + ((size_t)(b * CC + c) * HH) * WW + 4 * g;
            f32x4 v[8];
#pragma unroll
            for (int k = 0; k < 8; ++k) {
                const int r = h0 - 2 + k;
                v[k] = (r >= 0 && r < HH)
                     ? __builtin_nontemporal_load(reinterpret_cast<const f32x4*>(xc + r * WW))
                     : (f32x4){0.f, 0.f, 0.f, 0.f};
            }
#pragma unroll
            for (int j = 0; j < 4; ++j) {
                f32x4 a = {0.f, 0.f, 0.f, 0.f};
#pragma unroll
                for (int i = 0; i < 5; ++i) {
                    a[0] = fmaf(wn[i], v[j + i][0], a[0]);
                    a[1] = fmaf(wn[i], v[j + i][1], a[1]);
                    a[2] = fmaf(wn[i], v[j + i][2], a[2]);
                    a[3] = fmaf(wn[i], v[j + i][3], a[3]);
                }
                us4 bv;
                bv[0] = f2bf(a[0]); bv[1] = f2bf(a[1]);
                bv[2] = f2bf(a[2]); bv[3] = f2bf(a[3]);
                *reinterpret_cast<us4*>(&vb[c & 15][j][4 + 4 * g]) = bv;
            }
        }
        __syncthreads();

        // ---- phase 2: horizontal blur, 8 channels x 4 px per thread per j ----
        // thread -> (cu8 = t&1, px-quad p4 = (t>>1)&63, j-half = t>>7)
        const int cu8 = t & 1;
        const int p4  = (t >> 1) & 63;
        const int jh  = t >> 7;
        const int P   = p4 << 2;            // px base (multiple of 4)
        const int cl0 = cu8 << 3;           // local channel base in vb

#pragma unroll
        for (int jj = 0; jj < 2; ++jj) {
            const int j = (jh << 1) + jj;
            us8 o[4];                        // o[d] = 8 channels at px P+d
#pragma unroll
            for (int cc = 0; cc < 8; ++cc) {
                const unsigned short* vp = &vb[cl0 + cc][j][P];   // 8B-aligned
                us4 r0 = *reinterpret_cast<const us4*>(vp);
                us4 r1 = *reinterpret_cast<const us4*>(vp + 4);
                us4 r2 = *reinterpret_cast<const us4*>(vp + 8);
                float v[12];
#pragma unroll
                for (int q = 0; q < 4; ++q) {
                    v[q]     = bf2f(r0[q]);
                    v[4 + q] = bf2f(r1[q]);
                    v[8 + q] = bf2f(r2[q]);
                }
                // array idx P+q == px (P+q-4); output px P+d uses v[d+2..d+6]
#pragma unroll
                for (int d = 0; d < 4; ++d) {
                    float a = 0.0f;
#pragma unroll
                    for (int i = 0; i < 5; ++i) a = fmaf(wn[i], v[d + 2 + i], a);
                    o[d][cc] = f2bf(a);
                }
            }
            unsigned short* obj = xb_img + ((size_t)(h0 + PD + j) * WP + PD + P) * CC
                                         + (pass << 4) + cl0;
#pragma unroll
            for (int d = 0; d < 4; ++d)
                *reinterpret_cast<us8*>(obj + d * CC) = o[d];    // 16B coalesced
        }
    }
}

// ---------------------------------------------------------------------------
// Kernel 2: corner table (sorted by image offset) + pre-scaled B fragments.
// meta[37+e] = window-relative offset; meta[74] = shifts fit |Sy|,|Sx|<=7.
// (unchanged from R11)
// ---------------------------------------------------------------------------
__global__ void wtrans_kernel(const float* __restrict__ wgt,
                              const float* __restrict__ sigma_p,
                              int* __restrict__ meta,
                              unsigned short* __restrict__ wb2) {
    __shared__ int   s_tap[36];
    __shared__ float s_w[36];
    __shared__ int   s_soff[36];
    __shared__ int   s_wrel[36];
    __shared__ int   s_n;
    const int t = threadIdx.x;

    if (t == 0) {
        const float UY[9] = {-0.70710678f, -1.0f, -0.70710678f, 0.0f, 0.0f, 0.0f,
                              0.70710678f,  1.0f,  0.70710678f};
        const float UX[9] = {-0.70710678f, 0.0f, 0.70710678f, -1.0f, 0.0f, 1.0f,
                             -0.70710678f, 0.0f, 0.70710678f};
        const int KYI[9] = {-1, -1, -1, 0, 0, 0, 1, 1, 1};
        const int KXI[9] = {-1, 0, 1, -1, 0, 1, -1, 0, 1};
        const float s6 = sigma_p[0] * 6.0f;
        int n = 0, ok = 1;
        for (int s_ = 0; s_ < 9; ++s_) {
            float offy = UY[s_] * s6, offx = UX[s_] * s6;
            float fy = floorf(offy), fx = floorf(offx);
            float ty = offy - fy,    tx = offx - fx;
            int sy = KYI[s_] + (int)fy;
            int sx = KXI[s_] + (int)fx;
            float wy[2] = {1.0f - ty, ty};
            float wx[2] = {1.0f - tx, tx};
            for (int dy = 0; dy < 2; ++dy)
                for (int dx = 0; dx < 2; ++dx) {
                    float wc = wy[dy] * wx[dx];
                    if (wc != 0.0f) {
                        const int syc = sy + dy, sxc = sx + dx;
                        s_tap[n]  = s_;
                        s_w[n]    = wc;
                        s_soff[n] = (syc * WP + sxc) * CC;
                        s_wrel[n] = (syc + 7) * WCOLS + (sxc + 8);
                        if (syc < -7 || syc > 7 || sxc < -7 || sxc > 7) ok = 0;
                        ++n;
                    }
                }
        }
        // insertion sort by soff (== row-major (Sy,Sx) order; wrel co-sorts)
        for (int i = 1; i < n; ++i) {
            int ks = s_soff[i]; int kt = s_tap[i]; float kw = s_w[i]; int kr = s_wrel[i];
            int j = i - 1;
            while (j >= 0 && s_soff[j] > ks) {
                s_soff[j + 1] = s_soff[j]; s_tap[j + 1] = s_tap[j];
                s_w[j + 1] = s_w[j];       s_wrel[j + 1] = s_wrel[j];
                --j;
            }
            s_soff[j + 1] = ks; s_tap[j + 1] = kt; s_w[j + 1] = kw; s_wrel[j + 1] = kr;
        }
        if (blockIdx.x == 0) {
            meta[0] = n;
            for (int i = 0; i < n; ++i) { meta[1 + i] = s_soff[i]; meta[37 + i] = s_wrel[i]; }
            meta[74] = ok;
        }
        s_n = n;
    }
    __syncthreads();

    const int e = blockIdx.x;
    if (e >= s_n) return;
    for (int i = t; i < 1024; i += 256) {
        int j  = i & 7;
        int l  = (i >> 3) & 63;
        int nh = (i >> 9) & 1;
        int o  = nh * 16 + (l & 15);
        int c  = ((l >> 4) << 3) + j;
        wb2[e * 1024 + i] = f2bf(s_w[e] * wgt[(o * CC + c) * 9 + s_tap[e]]);
    }
}

// ---------------------------------------------------------------------------
// Kernel 3: LDS-STAGED stencil GEMM. (unchanged from R11 — 120us -> ~51us)
// ---------------------------------------------------------------------------
__global__ __launch_bounds__(512) void mix8_kernel(const unsigned short* __restrict__ xbt,
                                                   const int* __restrict__ meta,
                                                   const unsigned short* __restrict__ wb2,
                                                   float* __restrict__ out) {
    __shared__ bf16x8 win[4 * PLANE];        // 153,664 B
    const int t    = threadIdx.x;
    const int lane = t & 63;
    const int wv   = t >> 6;                 // 0..7
    const int blk  = ((blockIdx.x & 7) << 7) + (blockIdx.x >> 3);  // 1024 blocks, chunk 128
    const int xs   = blk & 3;
    const int band = (blk >> 2) & 15;
    const int b    = blk >> 6;
    const int h0   = band << 4;
    const int x0   = xs << 6;
    const int mrow = lane & 15;
    const int cu   = lane >> 4;              // channel-unit 0..3
    const int ncorn = meta[0];
    const int ok    = meta[74];

    const unsigned short* img = xbt + (size_t)b * (HP * WP * CC);

    f32x4 acc[8][2];                         // [ri*4+tx][half]
#pragma unroll
    for (int q = 0; q < 8; ++q) {
        acc[q][0] = (f32x4){0.f, 0.f, 0.f, 0.f};
        acc[q][1] = (f32x4){0.f, 0.f, 0.f, 0.f};
    }

    if (ok) {
        // ---- stage window: rows h0-7..h0+22 (padded h0+1..), px x0-8..x0+71 ----
        const unsigned short* gsrc = img + ((size_t)(h0 + 1) * WP + x0) * CC;
        for (int i = t; i < WROWS * WCOLS * 4; i += 512) {
            const int cui = i & 3;
            const int pxl = (i >> 2) % WCOLS;
            const int row = (i >> 2) / WCOLS;
            win[cui * PLANE + row * WCOLS + pxl] =
                *reinterpret_cast<const bf16x8*>(gsrc + ((size_t)row * WP + pxl) * CC + cui * 8);
        }
        __syncthreads();

        const int ubase = cu * PLANE + (wv * 2) * WCOLS + mrow;   // per-lane, loop-invariant
        for (int e = 0; e < ncorn; ++e) {
            const int ewr = meta[37 + e];                          // wave-uniform s_load
            const bf16x8 b0 = *reinterpret_cast<const bf16x8*>(wb2 + ((e * 2 + 0) * 64 + lane) * 8);
            const bf16x8 b1 = *reinterpret_cast<const bf16x8*>(wb2 + ((e * 2 + 1) * 64 + lane) * 8);
            const int abase = ubase + ewr;
#pragma unroll
            for (int ri = 0; ri < 2; ++ri) {
#pragma unroll
                for (int tx = 0; tx < 4; ++tx) {
                    const bf16x8 a = win[abase + ri * WCOLS + tx * 16];  // imm-foldable
                    acc[ri * 4 + tx][0] = __builtin_amdgcn_mfma_f32_16x16x32_bf16(a, b0, acc[ri * 4 + tx][0], 0, 0, 0);
                    acc[ri * 4 + tx][1] = __builtin_amdgcn_mfma_f32_16x16x32_bf16(a, b1, acc[ri * 4 + tx][1], 0, 0, 0);
                }
            }
        }
    } else {
        // generic fallback (any sigma): A straight from global
        const unsigned short* gb = img + ((size_t)(h0 + wv * 2 + PD) * WP + x0 + PD) * CC
                                       + mrow * CC + cu * 8;
        for (int e = 0; e < ncorn; ++e) {
            const int soff = meta[1 + e];
            const bf16x8 b0 = *reinterpret_cast<const bf16x8*>(wb2 + ((e * 2 + 0) * 64 + lane) * 8);
            const bf16x8 b1 = *reinterpret_cast<const bf16x8*>(wb2 + ((e * 2 + 1) * 64 + lane) * 8);
#pragma unroll
            for (int ri = 0; ri < 2; ++ri) {
#pragma unroll
                for (int tx = 0; tx < 4; ++tx) {
                    const bf16x8 a = *reinterpret_cast<const bf16x8*>(
                        gb + soff + ((size_t)ri * WP + tx * 16) * CC);
                    acc[ri * 4 + tx][0] = __builtin_amdgcn_mfma_f32_16x16x32_bf16(a, b0, acc[ri * 4 + tx][0], 0, 0, 0);
                    acc[ri * 4 + tx][1] = __builtin_amdgcn_mfma_f32_16x16x32_bf16(a, b1, acc[ri * 4 + tx][1], 0, 0, 0);
                }
            }
        }
    }

    // D: out channel = lane&15 (+16 for half1), pixel = x0 + tx*16 + (lane>>4)*4 + reg
    const int prow = cu << 2;
    float* op0 = out + ((size_t)b * OO + (lane & 15)) * HW;
#pragma unroll
    for (int ri = 0; ri < 2; ++ri) {
        float* opr = op0 + (size_t)(h0 + wv * 2 + ri) * WW + x0 + prow;
#pragma unroll
        for (int tx = 0; tx < 4; ++tx) {
            *reinterpret_cast<f32x4*>(opr + tx * 16) = acc[ri * 4 + tx][0];
            *reinterpret_cast<f32x4*>(opr + tx * 16 + (size_t)16 * HW) = acc[ri * 4 + tx][1];
        }
    }
}

// ---------------------------------------------------------------------------
extern "C" void kernel_launch(void* const* d_in, const int* in_sizes, int n_in,
                              void* d_out, int out_size, void* d_ws, size_t ws_size,
                              hipStream_t stream) {
    const float* x     = (const float*)d_in[0];
    const float* sigma = (const float*)d_in[1];
    const float* wgt   = (const float*)d_in[2];
    float* out = (float*)d_out;

    // ws layout: [ meta: 128 ints ][ wb2: 36*1024 bf16 ] (128 KB reserved)
    //            [ xbt: BB*HP*WP*CC bf16 padded image ]
    int* meta           = (int*)d_ws;
    unsigned short* wb2 = (unsigned short*)((char*)d_ws + 512);
    unsigned short* xbt = (unsigned short*)((char*)d_ws + 131072);

    wtrans_kernel<<<36, 256, 0, stream>>>(wgt, sigma, meta, wb2);
    blur_t_kernel<<<BB * 64, 256, 0, stream>>>(x, sigma, xbt);
    mix8_kernel<<<BB * 64, 512, 0, stream>>>(xbt, meta, wb2, out);
}